// Round 1
// baseline (134.089 us; speedup 1.0000x reference)
//
#include <hip/hip_runtime.h>
#include <hip/hip_bf16.h>

// Problem constants (fixed by setup_inputs)
#define B_ROWS 4096
#define N_COLS 16384   // B_s * topk
#define CDIM   128
#define NIDS   751
#define TEMP_INV 20.0f // 1 / 0.05

// Main-kernel tiling
#define BM 64                    // rows per block (4 waves x 16)
#define BN 64                    // cols per step
#define NCHUNK 8                 // column chunks (grid = 64 row-blocks x 8)
#define COLS_PER_CHUNK (N_COLS / NCHUNK)   // 2048
#define STEPS (COLS_PER_CHUNK / BN)        // 32

typedef __attribute__((ext_vector_type(8))) short short8;      // 8 bf16 (4 VGPRs)
typedef __attribute__((ext_vector_type(4))) float f32x4;
typedef __attribute__((ext_vector_type(4))) unsigned short u16x4;

#define AS1 __attribute__((address_space(1)))
#define AS3 __attribute__((address_space(3)))

__device__ __forceinline__ unsigned short f2bf(float x) {
  union { float f; unsigned u; } c; c.f = x;
  unsigned r = c.u + 0x7FFFu + ((c.u >> 16) & 1u);  // RNE
  return (unsigned short)(r >> 16);
}

// ---- fp32 -> bf16 conversion of feats and fs (flat) ----
__global__ void cvt_kernel(const float* __restrict__ fa, const float* __restrict__ fb,
                           unsigned short* __restrict__ oa, unsigned short* __restrict__ ob) {
  int idx = blockIdx.x * blockDim.x + threadIdx.x;
  const int NF4 = B_ROWS * CDIM / 4;
  if (idx < NF4) {
    f32x4 v = ((const f32x4*)fa)[idx];
    u16x4 o = { f2bf(v[0]), f2bf(v[1]), f2bf(v[2]), f2bf(v[3]) };
    ((u16x4*)oa)[idx] = o;
  } else {
    int j = idx - NF4;
    f32x4 v = ((const f32x4*)fb)[j];
    u16x4 o = { f2bf(v[0]), f2bf(v[1]), f2bf(v[2]), f2bf(v[3]) };
    ((u16x4*)ob)[j] = o;
  }
}

// ---- F[l] = sum of feats rows with label l (fp32, atomic) ----
__global__ void tableF_kernel(const float* __restrict__ feats, const int* __restrict__ labels,
                              float* __restrict__ Ftab) {
  int idx = blockIdx.x * blockDim.x + threadIdx.x;  // over 4096*128
  int row = idx >> 7, c = idx & 127;
  atomicAdd(&Ftab[labels[row] * CDIM + c], feats[idx]);
}

// ---- P[l] = count of labels_s == l ----
__global__ void pcnt_kernel(const int* __restrict__ labels_s, float* __restrict__ Pcnt) {
  int j = blockIdx.x * blockDim.x + threadIdx.x;    // over 16384
  atomicAdd(&Pcnt[labels_s[j]], 1.0f);
}

// ---- Main: row-wise online logsumexp of (feats @ fs^T) * TEMP_INV ----
__launch_bounds__(256, 2)
__global__ void lse_kernel(const unsigned short* __restrict__ A,   // feats bf16 [4096][128]
                           const unsigned short* __restrict__ Bm,  // fs bf16 [16384][128]
                           float* __restrict__ pm, float* __restrict__ ps) {
  __shared__ unsigned short lds[2][BN * CDIM];  // 2 x 16 KB
  const int tid = threadIdx.x;
  const int wv = tid >> 6, ln = tid & 63;
  const int ch = blockIdx.x & (NCHUNK - 1);     // chunk -> XCD affinity (bid%8)
  const int rb = blockIdx.x >> 3;               // row block 0..63
  const int col_base = ch * COLS_PER_CHUNK;

  // A fragments: wave's 16 rows x K=128 (4 frags). lane: row=ln&15, k=8*(ln>>4)+i
  const int arow = rb * BM + wv * 16 + (ln & 15);
  const unsigned short* aptr = A + (size_t)arow * CDIM + ((ln >> 4) * 8);
  short8 afr[4];
#pragma unroll
  for (int kk = 0; kk < 4; ++kk)
    afr[kk] = *(const short8*)(aptr + kk * 32);

  float m[4], s[4];
#pragma unroll
  for (int j = 0; j < 4; ++j) { m[j] = -1e30f; s[j] = 0.f; }

  // Stage BN x CDIM fs tile into lds[buf]; LDS dest linear, global src pre-swizzled
  // so LDS chunk cc of row holds global chunk cc^(row&7)  (T2 both-sides rule).
  auto stage = [&](int buf, int step) {
    const int c0 = col_base + step * BN;
    char* base = (char*)&lds[buf][0];
#pragma unroll
    for (int r = 0; r < 4; ++r) {
      int q = r * 256 + wv * 64 + ln;          // chunk 0..1023
      int row = q >> 4, cc = q & 15;
      int cs = cc ^ (row & 7);
      const unsigned short* src = Bm + (size_t)(c0 + row) * CDIM + cs * 8;
      __builtin_amdgcn_global_load_lds((AS1 const void*)src,
                                       (AS3 void*)(base + (size_t)(r * 256 + wv * 64) * 16),
                                       16, 0, 0);
    }
  };

  stage(0, 0);
  asm volatile("s_waitcnt vmcnt(0)" ::: "memory");
  __syncthreads();

  int cur = 0;
  for (int t = 0; t < STEPS; ++t) {
    if (t + 1 < STEPS) stage(cur ^ 1, t + 1);

    // 4 col-tiles of 16: acc[ct][j] = sim[row=4*(ln>>4)+j][ct*16 + (ln&15)]
    f32x4 acc[4];
#pragma unroll
    for (int ct = 0; ct < 4; ++ct) {
      const int rowT = ct * 16 + (ln & 15);
      f32x4 c4 = {0.f, 0.f, 0.f, 0.f};
#pragma unroll
      for (int kk = 0; kk < 4; ++kk) {
        int q = kk * 4 + (ln >> 4);
        int qs = q ^ (rowT & 7);
        short8 bf = *(const short8*)&lds[cur][rowT * CDIM + qs * 8];
        c4 = __builtin_amdgcn_mfma_f32_16x16x32_bf16(afr[kk], bf, c4, 0, 0, 0);
      }
      acc[ct] = c4;
    }

    // Per-lane online LSE update (no cross-lane ops in hot loop)
#pragma unroll
    for (int j = 0; j < 4; ++j) {
      float v0 = acc[0][j] * TEMP_INV, v1 = acc[1][j] * TEMP_INV;
      float v2 = acc[2][j] * TEMP_INV, v3 = acc[3][j] * TEMP_INV;
      float mx = fmaxf(fmaxf(v0, v1), fmaxf(v2, v3));
      float mn = fmaxf(m[j], mx);
      s[j] = s[j] * __expf(m[j] - mn) +
             (__expf(v0 - mn) + __expf(v1 - mn)) + (__expf(v2 - mn) + __expf(v3 - mn));
      m[j] = mn;
    }

    asm volatile("s_waitcnt vmcnt(0)" ::: "memory");
    __syncthreads();
    cur ^= 1;
  }

  // Combine (m,s) across the 16 lanes sharing ln>>4 (xor 1,2,4,8 stay in-group)
#pragma unroll
  for (int j = 0; j < 4; ++j) {
#pragma unroll
    for (int off = 1; off < 16; off <<= 1) {
      float mo = __shfl_xor(m[j], off, 64);
      float so = __shfl_xor(s[j], off, 64);
      float mn = fmaxf(m[j], mo);
      s[j] = s[j] * __expf(m[j] - mn) + so * __expf(mo - mn);
      m[j] = mn;
    }
  }

  if ((ln & 15) == 0) {
    int rbase = rb * BM + wv * 16 + (ln >> 4) * 4;
#pragma unroll
    for (int j = 0; j < 4; ++j) {
      pm[(size_t)ch * B_ROWS + rbase + j] = m[j];
      ps[(size_t)ch * B_ROWS + rbase + j] = s[j];
    }
  }
}

// ---- Combine per-chunk partials -> lse per row -> sum into acc[0] ----
__global__ void combine_kernel(const float* __restrict__ pm, const float* __restrict__ ps,
                               float* __restrict__ acc) {
  int row = blockIdx.x * blockDim.x + threadIdx.x;  // 16 blocks x 256
  float mg = -1e30f, sg = 0.f;
#pragma unroll
  for (int c = 0; c < NCHUNK; ++c) {
    float mp = pm[c * B_ROWS + row], sp = ps[c * B_ROWS + row];
    float mn = fmaxf(mg, mp);
    sg = sg * __expf(mg - mn) + sp * __expf(mp - mn);
    mg = mn;
  }
  float lse = mg + logf(sg);
#pragma unroll
  for (int off = 1; off < 64; off <<= 1) lse += __shfl_xor(lse, off, 64);
  __shared__ float wsum[4];
  if ((threadIdx.x & 63) == 0) wsum[threadIdx.x >> 6] = lse;
  __syncthreads();
  if (threadIdx.x == 0) atomicAdd(&acc[0], wsum[0] + wsum[1] + wsum[2] + wsum[3]);
}

// ---- Positive term: acc[1] = sum_j fs_j . F[ls_j] / P[ls_j]  (raw dot, no temp) ----
__global__ void posdot_kernel(const float* __restrict__ fs, const int* __restrict__ labels_s,
                              const float* __restrict__ Ftab, const float* __restrict__ Pcnt,
                              float* __restrict__ acc) {
  int j = blockIdx.x * blockDim.x + threadIdx.x;    // 64 blocks x 256 over 16384 rows
  int l = labels_s[j];
  const f32x4* fr = (const f32x4*)(fs + (size_t)j * CDIM);
  const f32x4* Fr = (const f32x4*)(Ftab + (size_t)l * CDIM);
  float d = 0.f;
#pragma unroll
  for (int q = 0; q < CDIM / 4; ++q) {
    f32x4 a = fr[q], b = Fr[q];
    d += a[0] * b[0] + a[1] * b[1] + a[2] * b[2] + a[3] * b[3];
  }
  d /= Pcnt[l];
#pragma unroll
  for (int off = 1; off < 64; off <<= 1) d += __shfl_xor(d, off, 64);
  __shared__ float wsum[4];
  if ((threadIdx.x & 63) == 0) wsum[threadIdx.x >> 6] = d;
  __syncthreads();
  if (threadIdx.x == 0) atomicAdd(&acc[1], wsum[0] + wsum[1] + wsum[2] + wsum[3]);
}

__global__ void finalize_kernel(const float* __restrict__ acc, float* __restrict__ out) {
  out[0] = (acc[0] - acc[1] * TEMP_INV) / (float)B_ROWS;
}

extern "C" void kernel_launch(void* const* d_in, const int* in_sizes, int n_in,
                              void* d_out, int out_size, void* d_ws, size_t ws_size,
                              hipStream_t stream) {
  const float* feats   = (const float*)d_in[0];
  const float* feats_s = (const float*)d_in[1];   // [16384][128] flat
  const int* labels    = (const int*)d_in[2];
  const int* labels_s  = (const int*)d_in[3];
  float* out = (float*)d_out;

  char* ws = (char*)d_ws;
  size_t off = 0;
  auto carve = [&](size_t bytes) -> char* {
    char* p = ws + off;
    off += (bytes + 255) & ~(size_t)255;
    return p;
  };
  unsigned short* feats_bf = (unsigned short*)carve((size_t)B_ROWS * CDIM * 2);  // 1 MB
  unsigned short* fs_bf    = (unsigned short*)carve((size_t)N_COLS * CDIM * 2);  // 4 MB
  float* Ftab = (float*)carve((size_t)NIDS * CDIM * 4);                          // 384 KB
  float* Pcnt = (float*)carve((size_t)NIDS * 4);
  float* pm   = (float*)carve((size_t)NCHUNK * B_ROWS * 4);
  float* ps   = (float*)carve((size_t)NCHUNK * B_ROWS * 4);
  float* acc  = (float*)carve(2 * 4);

  hipMemsetAsync(Ftab, 0, (size_t)NIDS * CDIM * 4, stream);
  hipMemsetAsync(Pcnt, 0, (size_t)NIDS * 4, stream);
  hipMemsetAsync(acc, 0, 2 * 4, stream);

  const int NF4 = B_ROWS * CDIM / 4, NS4 = N_COLS * CDIM / 4;
  cvt_kernel<<<(NF4 + NS4) / 256, 256, 0, stream>>>(feats, feats_s, feats_bf, fs_bf);
  tableF_kernel<<<(B_ROWS * CDIM) / 256, 256, 0, stream>>>(feats, labels, Ftab);
  pcnt_kernel<<<N_COLS / 256, 256, 0, stream>>>(labels_s, Pcnt);

  lse_kernel<<<(B_ROWS / BM) * NCHUNK, 256, 0, stream>>>(feats_bf, fs_bf, pm, ps);

  combine_kernel<<<B_ROWS / 256, 256, 0, stream>>>(pm, ps, acc);
  posdot_kernel<<<N_COLS / 256, 256, 0, stream>>>(feats_s, labels_s, Ftab, Pcnt, acc);
  finalize_kernel<<<1, 1, 0, stream>>>(acc, out);
}

// Round 2
// 112.673 us; speedup vs baseline: 1.1901x; 1.1901x over previous
//
#include <hip/hip_runtime.h>
#include <hip/hip_bf16.h>

// Problem constants (fixed by setup_inputs)
#define B_ROWS 4096
#define N_COLS 16384   // B_s * topk
#define CDIM   128
#define NIDS   751
#define TEMP_INV 20.0f
#define ASCALE 28.853900817779268f  // 20 * log2(e): fold temp + ln->log2 into A
#define LN2 0.6931471805599453f

// lse tiling: BM=256 rows/block (4 waves x 4 row-frags of 16), BN=64 cols/step
#define BM 256
#define BN 64
#define NCHUNK 32
#define COLS_PER_CHUNK (N_COLS / NCHUNK)   // 512
#define STEPS (COLS_PER_CHUNK / BN)        // 8
#define LSE_BLOCKS ((B_ROWS / BM) * NCHUNK)  // 16 * 32 = 512 -> 2 blocks/CU
#define POS_BLOCKS (N_COLS / 256)            // 64

typedef __attribute__((ext_vector_type(8))) short short8;      // 8 bf16
typedef __attribute__((ext_vector_type(4))) float f32x4;
typedef __attribute__((ext_vector_type(4))) unsigned short u16x4;

#define AS1 __attribute__((address_space(1)))
#define AS3 __attribute__((address_space(3)))

__device__ __forceinline__ unsigned short f2bf(float x) {
  union { float f; unsigned u; } c; c.f = x;
  unsigned r = c.u + 0x7FFFu + ((c.u >> 16) & 1u);  // RNE
  return (unsigned short)(r >> 16);
}

// ---- prep: cvt (feats*ASCALE -> bf16, fs -> bf16) + F-table + P-count ----
__global__ void prep_kernel(const float* __restrict__ feats, const float* __restrict__ fs,
                            const int* __restrict__ labels, const int* __restrict__ labels_s,
                            unsigned short* __restrict__ feats_bf, unsigned short* __restrict__ fs_bf,
                            float* __restrict__ Ftab, float* __restrict__ Pcnt) {
  const int bid = blockIdx.x;
  const int NF4 = B_ROWS * CDIM / 4;     // 131072
  const int NCVT_BLK = (NF4 + N_COLS * CDIM / 4) / 256;  // 2560
  if (bid < NCVT_BLK) {
    int idx = bid * 256 + threadIdx.x;
    if (idx < NF4) {
      f32x4 v = ((const f32x4*)feats)[idx];
      u16x4 o = { f2bf(v[0] * ASCALE), f2bf(v[1] * ASCALE), f2bf(v[2] * ASCALE), f2bf(v[3] * ASCALE) };
      ((u16x4*)feats_bf)[idx] = o;
    } else {
      int j = idx - NF4;
      f32x4 v = ((const f32x4*)fs)[j];
      u16x4 o = { f2bf(v[0]), f2bf(v[1]), f2bf(v[2]), f2bf(v[3]) };
      ((u16x4*)fs_bf)[j] = o;
    }
  } else if (bid < NCVT_BLK + (B_ROWS * CDIM) / 256) {   // 2048 blocks: F-table
    int idx = (bid - NCVT_BLK) * 256 + threadIdx.x;
    int row = idx >> 7, c = idx & 127;
    atomicAdd(&Ftab[labels[row] * CDIM + c], feats[idx]);
  } else {                                                // 64 blocks: P-count
    int j = (bid - NCVT_BLK - (B_ROWS * CDIM) / 256) * 256 + threadIdx.x;
    atomicAdd(&Pcnt[labels_s[j]], 1.0f);
  }
}

// ---- main: lse (blocks 0..511) + posdot (blocks 512..575) ----
__launch_bounds__(256, 2)
__global__ void main_kernel(const unsigned short* __restrict__ A,   // feats bf16 (pre-scaled)
                            const unsigned short* __restrict__ Bm,  // fs bf16
                            const float* __restrict__ fs32,
                            const int* __restrict__ labels_s,
                            const float* __restrict__ Ftab, const float* __restrict__ Pcnt,
                            float* __restrict__ pm, float* __restrict__ ps,
                            float* __restrict__ acc) {
  __shared__ unsigned short lds[2][BN * CDIM];  // 2 x 16 KB
  __shared__ float wsum[4];

  if (blockIdx.x >= LSE_BLOCKS) {
    // -------- posdot: acc[1] += sum_j fs_j . F[ls_j] / P[ls_j] (fp32 exact) --------
    int j = (blockIdx.x - LSE_BLOCKS) * 256 + threadIdx.x;
    int l = labels_s[j];
    const f32x4* fr = (const f32x4*)(fs32 + (size_t)j * CDIM);
    const f32x4* Fr = (const f32x4*)(Ftab + (size_t)l * CDIM);
    float d = 0.f;
#pragma unroll
    for (int q = 0; q < CDIM / 4; ++q) {
      f32x4 a = fr[q], b = Fr[q];
      d += a[0] * b[0] + a[1] * b[1] + a[2] * b[2] + a[3] * b[3];
    }
    d /= Pcnt[l];
#pragma unroll
    for (int off = 1; off < 64; off <<= 1) d += __shfl_xor(d, off, 64);
    if ((threadIdx.x & 63) == 0) wsum[threadIdx.x >> 6] = d;
    __syncthreads();
    if (threadIdx.x == 0) atomicAdd(&acc[1], wsum[0] + wsum[1] + wsum[2] + wsum[3]);
    return;
  }

  // -------- lse: online log2-sum-exp2 of feats_scaled @ fs^T --------
  const int tid = threadIdx.x, wv = tid >> 6, ln = tid & 63;
  const int hi = ln >> 4, lo = ln & 15;
  const int ch = blockIdx.x & (NCHUNK - 1);   // chunk -> XCD affinity (bid%8 const per chunk)
  const int rb = blockIdx.x >> 5;             // row block 0..15
  const int col_base = ch * COLS_PER_CHUNK;

  // A fragments: wave rows wv*64 + rg*16 + lo; k = hi*8 + kk*32
  const unsigned short* aptr = A + (size_t)(rb * BM + wv * 64 + lo) * CDIM + hi * 8;
  short8 afr[4][4];  // [rg][kk]
#pragma unroll
  for (int rg = 0; rg < 4; ++rg)
#pragma unroll
    for (int kk = 0; kk < 4; ++kk)
      afr[rg][kk] = *(const short8*)(aptr + rg * 16 * CDIM + kk * 32);

  float m_[4][4], s_[4][4];  // per-lane state, log2 domain; row = rg*16 + hi*4 + j
#pragma unroll
  for (int rg = 0; rg < 4; ++rg)
#pragma unroll
    for (int j = 0; j < 4; ++j) { m_[rg][j] = -1e30f; s_[rg][j] = 0.f; }

  // Stage BN x CDIM fs tile; LDS linear dest, global src pre-swizzled (chunk^row&7)
  auto stage = [&](int buf, int step) {
    const int c0 = col_base + step * BN;
    char* base = (char*)&lds[buf][0];
#pragma unroll
    for (int r = 0; r < 4; ++r) {
      int q = r * 256 + wv * 64 + ln;
      int row = q >> 4, cc = q & 15;
      int cs = cc ^ (row & 7);
      const unsigned short* src = Bm + (size_t)(c0 + row) * CDIM + cs * 8;
      __builtin_amdgcn_global_load_lds((AS1 const void*)src,
                                       (AS3 void*)(base + (size_t)(r * 256 + wv * 64) * 16),
                                       16, 0, 0);
    }
  };

  stage(0, 0);
  int cur = 0;
  for (int t = 0; t < STEPS; ++t) {
    if (t + 1 < STEPS) {
      stage(cur ^ 1, t + 1);                               // 4 new loads in flight
      asm volatile("s_waitcnt vmcnt(4)" ::: "memory");     // wait only cur's loads
    } else {
      asm volatile("s_waitcnt vmcnt(0)" ::: "memory");
    }
    __builtin_amdgcn_s_barrier();
    __builtin_amdgcn_sched_barrier(0);

    f32x4 accv[4][4];  // [rg][ct]
#pragma unroll
    for (int ct = 0; ct < 4; ++ct) {
      const int rowT = ct * 16 + lo;
      short8 bf[4];
#pragma unroll
      for (int kk = 0; kk < 4; ++kk) {
        int q = kk * 4 + hi;
        int qs = q ^ (rowT & 7);
        bf[kk] = *(const short8*)&lds[cur][rowT * CDIM + qs * 8];
      }
#pragma unroll
      for (int rg = 0; rg < 4; ++rg) {
        f32x4 c4 = {0.f, 0.f, 0.f, 0.f};
#pragma unroll
        for (int kk = 0; kk < 4; ++kk)
          c4 = __builtin_amdgcn_mfma_f32_16x16x32_bf16(afr[rg][kk], bf[kk], c4, 0, 0, 0);
        accv[rg][ct] = c4;  // z = sim*20*log2e; row=rg*16+hi*4+j, col=ct*16+lo
      }
    }

    // Per-lane online LSE in log2 domain (exp2 = 1 v_exp_f32, no muls)
#pragma unroll
    for (int rg = 0; rg < 4; ++rg)
#pragma unroll
      for (int j = 0; j < 4; ++j) {
        float v0 = accv[rg][0][j], v1 = accv[rg][1][j];
        float v2 = accv[rg][2][j], v3 = accv[rg][3][j];
        float mx = fmaxf(fmaxf(v0, v1), fmaxf(v2, v3));
        float mn = fmaxf(m_[rg][j], mx);
        s_[rg][j] = s_[rg][j] * __builtin_amdgcn_exp2f(m_[rg][j] - mn)
                  + (__builtin_amdgcn_exp2f(v0 - mn) + __builtin_amdgcn_exp2f(v1 - mn))
                  + (__builtin_amdgcn_exp2f(v2 - mn) + __builtin_amdgcn_exp2f(v3 - mn));
        m_[rg][j] = mn;
      }

    __builtin_amdgcn_sched_barrier(0);
    __builtin_amdgcn_s_barrier();
    cur ^= 1;
  }

  // Combine across the 16 lanes sharing hi (cols); xor 1,2,4,8 stay in-group
#pragma unroll
  for (int rg = 0; rg < 4; ++rg)
#pragma unroll
    for (int j = 0; j < 4; ++j) {
#pragma unroll
      for (int off = 1; off < 16; off <<= 1) {
        float mo = __shfl_xor(m_[rg][j], off, 64);
        float so = __shfl_xor(s_[rg][j], off, 64);
        float mn = fmaxf(m_[rg][j], mo);
        s_[rg][j] = s_[rg][j] * __builtin_amdgcn_exp2f(m_[rg][j] - mn)
                  + so * __builtin_amdgcn_exp2f(mo - mn);
        m_[rg][j] = mn;
      }
    }

  if (lo == 0) {
    int rbase = rb * BM + wv * 64;
#pragma unroll
    for (int rg = 0; rg < 4; ++rg)
#pragma unroll
      for (int j = 0; j < 4; ++j) {
        int row = rbase + rg * 16 + hi * 4 + j;
        pm[(size_t)ch * B_ROWS + row] = m_[rg][j];
        ps[(size_t)ch * B_ROWS + row] = s_[rg][j];
      }
  }
}

// ---- combine chunks -> lse_nat per row -> global sum -> finalize (last block) ----
__global__ void combine_kernel(const float* __restrict__ pm, const float* __restrict__ ps,
                               float* __restrict__ acc, float* __restrict__ out) {
  int row = blockIdx.x * blockDim.x + threadIdx.x;  // 16 blocks x 256
  float mg = -1e30f, sg = 0.f;
#pragma unroll
  for (int c = 0; c < NCHUNK; ++c) {
    float mp = pm[c * B_ROWS + row], sp = ps[c * B_ROWS + row];
    float mn = fmaxf(mg, mp);
    sg = sg * __builtin_amdgcn_exp2f(mg - mn) + sp * __builtin_amdgcn_exp2f(mp - mn);
    mg = mn;
  }
  float lse = LN2 * mg + logf(sg);  // back to natural log
#pragma unroll
  for (int off = 1; off < 64; off <<= 1) lse += __shfl_xor(lse, off, 64);
  __shared__ float wsum[4];
  if ((threadIdx.x & 63) == 0) wsum[threadIdx.x >> 6] = lse;
  __syncthreads();
  if (threadIdx.x == 0) {
    atomicAdd(&acc[0], wsum[0] + wsum[1] + wsum[2] + wsum[3]);
    __threadfence();
    unsigned old = atomicAdd((unsigned*)&acc[2], 1u);
    if (old == (B_ROWS / 256) - 1) {  // last block finalizes
      float a0 = atomicAdd(&acc[0], 0.f);
      float a1 = atomicAdd(&acc[1], 0.f);
      out[0] = (a0 - TEMP_INV * a1) * (1.0f / (float)B_ROWS);
    }
  }
}

extern "C" void kernel_launch(void* const* d_in, const int* in_sizes, int n_in,
                              void* d_out, int out_size, void* d_ws, size_t ws_size,
                              hipStream_t stream) {
  const float* feats   = (const float*)d_in[0];
  const float* feats_s = (const float*)d_in[1];   // [16384][128] flat
  const int* labels    = (const int*)d_in[2];
  const int* labels_s  = (const int*)d_in[3];
  float* out = (float*)d_out;

  char* ws = (char*)d_ws;
  size_t off = 0;
  auto carve = [&](size_t bytes) -> char* {
    char* p = ws + off;
    off += (bytes + 255) & ~(size_t)255;
    return p;
  };
  unsigned short* feats_bf = (unsigned short*)carve((size_t)B_ROWS * CDIM * 2);  // 1 MB
  unsigned short* fs_bf    = (unsigned short*)carve((size_t)N_COLS * CDIM * 2);  // 4 MB
  size_t zstart = off;
  float* Ftab = (float*)carve((size_t)NIDS * CDIM * 4);                          // 384 KB
  float* Pcnt = (float*)carve((size_t)NIDS * 4);
  float* acc  = (float*)carve(4 * 4);   // [0]=lse sum, [1]=pos sum, [2]=counter
  size_t zend = off;
  float* pm   = (float*)carve((size_t)NCHUNK * B_ROWS * 4);                      // 512 KB
  float* ps   = (float*)carve((size_t)NCHUNK * B_ROWS * 4);

  hipMemsetAsync(ws + zstart, 0, zend - zstart, stream);  // one fill for all zeroed state

  const int NPREP = (B_ROWS * CDIM / 4 + N_COLS * CDIM / 4) / 256   // cvt 2560
                  + (B_ROWS * CDIM) / 256                            // tableF 2048
                  + N_COLS / 256;                                    // pcnt 64
  prep_kernel<<<NPREP, 256, 0, stream>>>(feats, feats_s, labels, labels_s,
                                         feats_bf, fs_bf, Ftab, Pcnt);
  main_kernel<<<LSE_BLOCKS + POS_BLOCKS, 256, 0, stream>>>(feats_bf, fs_bf, feats_s, labels_s,
                                                           Ftab, Pcnt, pm, ps, acc);
  combine_kernel<<<B_ROWS / 256, 256, 0, stream>>>(pm, ps, acc, out);
}